// Round 12
// baseline (419.817 us; speedup 1.0000x reference)
//
#include <hip/hip_runtime.h>
#include <hip/hip_bf16.h>

namespace {

typedef __attribute__((ext_vector_type(8))) short short8v;   // 8 bf16
typedef __attribute__((ext_vector_type(4))) float float4v;   // 4 f32

// ---- workspace layout (float-slot offsets), ALL-BATCH fused ----
// B=4, H=16, N=4096, D=64, r=256. 221.4 MB total (ws >= 222.6 MB proven r1).
// FIX r12: V region is 8,388,608 slots; XH_OFF was 37748736 (overlapped V!).
constexpr size_t QHI_OFF  = 0;                       // ushort [4][16][4096][64]
constexpr size_t QLO_OFF  = 8388608;
constexpr size_t KHI_OFF  = 16777216;
constexpr size_t KLO_OFF  = 25165824;
constexpr size_t ATTNB_OFF = KHI_OFF;                // overlay (khi/klo dead after pass_a)
constexpr size_t V_OFF    = 33554432;                // ushort [4][16][4096][64]
constexpr size_t XH_OFF   = 41943040;                // ushort [16384][1024]
constexpr size_t KVP_OFF  = XH_OFF;                  // overlay (xh dead after qkv)
constexpr size_t NSQK_OFF = 50331648;                // f32 [4][16][4096]
constexpr size_t NSQQ_OFF = 50593792;                // f32 [4][16][4096]
constexpr size_t DPART_OFF = 50855936;               // f32 [4][16nc][16h][256]
constexpr size_t KVT_OFF  = 51118080;                // ushort [4][16h][64][256]
constexpr size_t DENV_OFF = 51642368;                // f32 [4][16h][256]
constexpr size_t WH_OFF   = 51658752;                // ushort Wqkv hi
constexpr size_t WL_OFF   = 53231616;                // ushort Wqkv lo
constexpr size_t WRMH_OFF = 54804480;                // ushort Wrm hi
constexpr size_t WRML_OFF = 54812672;
constexpr size_t WPH_OFF  = 54820864;                // ushort Wproj hi
constexpr size_t WS_ELEMS = 55345152;                // ~221.4 MB

__device__ __forceinline__ unsigned short f2bf(float f) {
  unsigned int u = __float_as_uint(f);
  u += 0x7FFFu + ((u >> 16) & 1u);                   // round-to-nearest-even
  return (unsigned short)(u >> 16);
}
__device__ __forceinline__ float bf2f(unsigned short u) {
  return __uint_as_float((unsigned)u << 16);
}

__global__ void k_sent(float* out, float v) { out[0] = v; }

// ---------------- fp32 -> bf16 hi+lo split (weights)
__global__ __launch_bounds__(256) void k_conv_split(
    const float* __restrict__ src, unsigned short* __restrict__ hi,
    unsigned short* __restrict__ lo, int n4) {
  int i = blockIdx.x * 256 + threadIdx.x;
  if (i >= n4) return;
  float4 v = *(const float4*)&src[(size_t)i * 4];
  ushort4 h, l;
  h.x = f2bf(v.x); l.x = f2bf(v.x - bf2f(h.x));
  h.y = f2bf(v.y); l.y = f2bf(v.y - bf2f(h.y));
  h.z = f2bf(v.z); l.z = f2bf(v.z - bf2f(h.z));
  h.w = f2bf(v.w); l.w = f2bf(v.w - bf2f(h.w));
  *(ushort4*)&hi[(size_t)i * 4] = h;
  *(ushort4*)&lo[(size_t)i * 4] = l;
}

__global__ __launch_bounds__(256) void k_conv_hi(
    const float* __restrict__ src, unsigned short* __restrict__ hi, int n4) {
  int i = blockIdx.x * 256 + threadIdx.x;
  if (i >= n4) return;
  float4 v = *(const float4*)&src[(size_t)i * 4];
  ushort4 h = {f2bf(v.x), f2bf(v.y), f2bf(v.z), f2bf(v.w)};
  *(ushort4*)&hi[(size_t)i * 4] = h;
}

// ---- stage [128 rows][64 k] bf16 tile via global_load_lds (verified) ----
__device__ __forceinline__ void stage_tile(const unsigned short* __restrict__ src,
                                           unsigned short* __restrict__ dst,
                                           int t) {
#pragma unroll
  for (int i = 0; i < 4; ++i) {
    int c = i * 256 + t;
    int row = c >> 3;
    int seg = (c & 7) ^ (row & 7);
    __builtin_amdgcn_global_load_lds(
        (const __attribute__((address_space(1))) void*)(src + (size_t)row * 1024 + seg * 8),
        (__attribute__((address_space(3))) void*)(dst + (size_t)c * 8),
        16, 0, 0);
  }
}

// ---- stage [32 rows][64 cols] bf16 tile (row-stride 64) via global_load_lds
__device__ __forceinline__ void stage_tile32(const unsigned short* __restrict__ src,
                                             unsigned short* __restrict__ dst,
                                             int t) {
  int row = t >> 3;
  int seg = (t & 7) ^ (row & 7);
  __builtin_amdgcn_global_load_lds(
      (const __attribute__((address_space(1))) void*)(src + (size_t)row * 64 + seg * 8),
      (__attribute__((address_space(3))) void*)(dst + (size_t)t * 8),
      16, 0, 0);
}

__device__ __forceinline__ short8v read_frag(const unsigned short* lds, int row,
                                             int seg) {
  return *(const short8v*)&lds[(size_t)row * 64 + ((seg ^ (row & 7)) * 8)];
}

// ---------------- qkv GEMM q/k (j<2048): 2-MFMA; epilogue -> hi/lo + nsq
__global__ __launch_bounds__(256, 2) void k_qkv_mfma(
    const unsigned short* __restrict__ xh,
    const unsigned short* __restrict__ wh, const unsigned short* __restrict__ wl,
    const float* __restrict__ bq, unsigned short* __restrict__ qhi_g,
    unsigned short* __restrict__ qlo_g, unsigned short* __restrict__ khi_g,
    unsigned short* __restrict__ klo_g, float* __restrict__ nsqq,
    float* __restrict__ nsqk) {
  __shared__ unsigned short ldsA[8192];
  __shared__ unsigned short ldsB[2][8192];
  const int t = threadIdx.x;
  const int lane = t & 63, wv = t >> 6;
  const int wm = wv >> 1, wn = wv & 1;
  const int lr = lane & 15, lg = lane >> 4;
  // XCD m-colocate: same-m blocks -> flat ≡ m (mod 8) -> same XCD L2
  const int flat = blockIdx.y * 16 + blockIdx.x;      // grid (16,128) = 2048
  const int mBase = (flat & 127) * 128;
  const int jBase = (flat >> 7) * 128;                // < 2048 (q/k)
  const int gb = mBase >> 12;
  const int nn0 = mBase & 4095;
  float4v acc[4][4];
#pragma unroll
  for (int a = 0; a < 4; ++a)
#pragma unroll
    for (int b = 0; b < 4; ++b) acc[a][b] = (float4v){0.f, 0.f, 0.f, 0.f};

  for (int kt = 0; kt < 1024; kt += 64) {
    __syncthreads();
    stage_tile(xh + (size_t)mBase * 1024 + kt, ldsA, t);
    stage_tile(wh + (size_t)jBase * 1024 + kt, ldsB[0], t);
    stage_tile(wl + (size_t)jBase * 1024 + kt, ldsB[1], t);
    asm volatile("s_waitcnt vmcnt(0)");
    __syncthreads();
#pragma unroll
    for (int ks = 0; ks < 2; ++ks) {
      const int seg = ks * 4 + lg;
      short8v ah[4], bh[4], bl[4];
#pragma unroll
      for (int f = 0; f < 4; ++f) {
        ah[f] = read_frag(ldsA, wm * 64 + f * 16 + lr, seg);
        int rb = wn * 64 + f * 16 + lr;
        bh[f] = read_frag(ldsB[0], rb, seg);
        bl[f] = read_frag(ldsB[1], rb, seg);
      }
#pragma unroll
      for (int fm = 0; fm < 4; ++fm)
#pragma unroll
        for (int fn = 0; fn < 4; ++fn) {
          acc[fm][fn] = __builtin_amdgcn_mfma_f32_16x16x32_bf16(
              ah[fm], bh[fn], acc[fm][fn], 0, 0, 0);
          acc[fm][fn] = __builtin_amdgcn_mfma_f32_16x16x32_bf16(
              ah[fm], bl[fn], acc[fm][fn], 0, 0, 0);
        }
    }
  }
  // epilogue: hi/lo split + row norm-sq (identical fp32 values as r10)
  const int t3 = jBase >> 10;                         // 0=q, 1=k (block-uniform)
  const int h = ((jBase + wn * 64) >> 6) & 15;
  float biasv[4];
#pragma unroll
  for (int fn = 0; fn < 4; ++fn)
    biasv[fn] = bq[jBase + wn * 64 + fn * 16 + lr];
  size_t hb = ((size_t)gb * 16 + h) * 262144;
  unsigned short* oh = (t3 ? khi_g : qhi_g) + hb;
  unsigned short* ol = (t3 ? klo_g : qlo_g) + hb;
  float* nsp = (t3 ? nsqk : nsqq) + ((size_t)gb * 16 + h) * 4096;
#pragma unroll
  for (int fm = 0; fm < 4; ++fm)
#pragma unroll
    for (int r = 0; r < 4; ++r) {
      int n = nn0 + wm * 64 + fm * 16 + lg * 4 + r;
      float s = 0.f;
#pragma unroll
      for (int fn = 0; fn < 4; ++fn) {
        float val = acc[fm][fn][r] + biasv[fn];
        int dd = fn * 16 + lr;
        unsigned short hu = f2bf(val);
        oh[(size_t)n * 64 + dd] = hu;
        ol[(size_t)n * 64 + dd] = f2bf(val - bf2f(hu));
        s = fmaf(val, val, s);
      }
      s += __shfl_xor(s, 1); s += __shfl_xor(s, 2);
      s += __shfl_xor(s, 4); s += __shfl_xor(s, 8);
      if (lr == 0) nsp[n] = 0.5f * s;
    }
}

// ---------------- qkv GEMM v (j in [2048,3072)): plain bf16, XCD swizzle
__global__ __launch_bounds__(256, 2) void k_qkv_v(
    const unsigned short* __restrict__ xh, const unsigned short* __restrict__ wh,
    const float* __restrict__ bq, unsigned short* __restrict__ vb) {
  __shared__ unsigned short ldsA[8192];
  __shared__ unsigned short ldsB[8192];
  const int t = threadIdx.x;
  const int lane = t & 63, wv = t >> 6;
  const int wm = wv >> 1, wn = wv & 1;
  const int lr = lane & 15, lg = lane >> 4;
  const int flat = blockIdx.y * 8 + blockIdx.x;       // grid (8,128) = 1024
  const int mBase = (flat & 127) * 128;
  const int jBase = 2048 + (flat >> 7) * 128;
  const int gb = mBase >> 12;
  const int nn0 = mBase & 4095;
  float4v acc[4][4];
#pragma unroll
  for (int a = 0; a < 4; ++a)
#pragma unroll
    for (int b = 0; b < 4; ++b) acc[a][b] = (float4v){0.f, 0.f, 0.f, 0.f};

  for (int kt = 0; kt < 1024; kt += 64) {
    __syncthreads();
    stage_tile(xh + (size_t)mBase * 1024 + kt, ldsA, t);
    stage_tile(wh + (size_t)jBase * 1024 + kt, ldsB, t);
    asm volatile("s_waitcnt vmcnt(0)");
    __syncthreads();
#pragma unroll
    for (int ks = 0; ks < 2; ++ks) {
      const int seg = ks * 4 + lg;
      short8v a[4], b[4];
#pragma unroll
      for (int f = 0; f < 4; ++f) {
        a[f] = read_frag(ldsA, wm * 64 + f * 16 + lr, seg);
        b[f] = read_frag(ldsB, wn * 64 + f * 16 + lr, seg);
      }
#pragma unroll
      for (int fm = 0; fm < 4; ++fm)
#pragma unroll
        for (int fn = 0; fn < 4; ++fn)
          acc[fm][fn] = __builtin_amdgcn_mfma_f32_16x16x32_bf16(
              a[fm], b[fn], acc[fm][fn], 0, 0, 0);
    }
  }
#pragma unroll
  for (int fn = 0; fn < 4; ++fn) {
    int j = jBase + wn * 64 + fn * 16 + lr;
    int h = (j >> 6) & 15, dd = j & 63;
    float bias = bq[j];
    unsigned short* op = vb + (size_t)gb * 4194304 + (size_t)h * 262144 + dd;
#pragma unroll
    for (int fm = 0; fm < 4; ++fm) {
      int n0 = nn0 + wm * 64 + fm * 16 + lg * 4;
#pragma unroll
      for (int r = 0; r < 4; ++r)
        op[(size_t)(n0 + r) * 64] = f2bf(acc[fm][fn][r] + bias);
    }
  }
}

// ---------------- pass A: phi_k (split MFMA, gload_lds-staged) + KV MFMA
__global__ __launch_bounds__(256) void k_pass_a_mfma(
    const unsigned short* __restrict__ khi_g,
    const unsigned short* __restrict__ klo_g, const float* __restrict__ nsqk,
    const unsigned short* __restrict__ vbb,
    const unsigned short* __restrict__ wrmh,
    const unsigned short* __restrict__ wrml, unsigned short* __restrict__ kvp,
    float* __restrict__ dpart) {
  __shared__ __align__(16) unsigned short sKhi[2048];   // 32x64 swizzled
  __shared__ __align__(16) unsigned short sKlo[2048];
  __shared__ __align__(16) unsigned short vT[64][40];
  __shared__ __align__(16) unsigned short phL[256][40];
  __shared__ __align__(16) float nsL[32];
  const int t = threadIdx.x;
  const int lane = t & 63, wv = t >> 6;
  const int lr = lane & 15, lg = lane >> 4;
  const int nc = blockIdx.x, h = blockIdx.y, gb = blockIdx.z;
  const unsigned short* kbh = khi_g + ((size_t)gb * 16 + h) * 262144;
  const unsigned short* kbl = klo_g + ((size_t)gb * 16 + h) * 262144;
  const float* nsb = nsqk + ((size_t)gb * 16 + h) * 4096;
  const unsigned short* vbh = vbb + (size_t)gb * 4194304 + (size_t)h * 262144;
  float4v acc[4][4];
#pragma unroll
  for (int a = 0; a < 4; ++a)
#pragma unroll
    for (int b = 0; b < 4; ++b) acc[a][b] = (float4v){0.f, 0.f, 0.f, 0.f};
  float dacc[4] = {};

  for (int tile = 0; tile < 8; ++tile) {
    const int n0 = nc * 256 + tile * 32;
    __syncthreads();
    stage_tile32(kbh + (size_t)n0 * 64, sKhi, t);
    stage_tile32(kbl + (size_t)n0 * 64, sKlo, t);
    {  // stage v (bf16) transposed
      int sn = t & 31, sd = (t >> 5) * 8;
      short8v v8 = *(const short8v*)&vbh[(size_t)(n0 + sn) * 64 + sd];
#pragma unroll
      for (int j = 0; j < 8; ++j) vT[sd + j][sn] = (unsigned short)v8[j];
    }
    if (t < 32) nsL[t] = nsb[n0 + t];
    asm volatile("s_waitcnt vmcnt(0)");
    __syncthreads();
    float4v p[2][4];
#pragma unroll
    for (int a = 0; a < 2; ++a)
#pragma unroll
      for (int b = 0; b < 4; ++b) p[a][b] = (float4v){0.f, 0.f, 0.f, 0.f};
#pragma unroll
    for (int ks = 0; ks < 2; ++ks) {
      short8v ah[2], al[2];
#pragma unroll
      for (int nf = 0; nf < 2; ++nf) {
        ah[nf] = read_frag(sKhi, nf * 16 + lr, ks * 4 + lg);
        al[nf] = read_frag(sKlo, nf * 16 + lr, ks * 4 + lg);
      }
#pragma unroll
      for (int rf = 0; rf < 4; ++rf) {
        size_t wo = (size_t)(wv * 64 + rf * 16 + lr) * 64 + ks * 32 + lg * 8;
        short8v bh = *(const short8v*)&wrmh[wo];
        short8v bl = *(const short8v*)&wrml[wo];
#pragma unroll
        for (int nf = 0; nf < 2; ++nf) {
          p[nf][rf] = __builtin_amdgcn_mfma_f32_16x16x32_bf16(ah[nf], bh, p[nf][rf], 0, 0, 0);
          p[nf][rf] = __builtin_amdgcn_mfma_f32_16x16x32_bf16(ah[nf], bl, p[nf][rf], 0, 0, 0);
          p[nf][rf] = __builtin_amdgcn_mfma_f32_16x16x32_bf16(al[nf], bh, p[nf][rf], 0, 0, 0);
        }
      }
    }
#pragma unroll
    for (int nf = 0; nf < 2; ++nf) {
      float4 ns4 = *(const float4*)&nsL[nf * 16 + lg * 4];
      float nsa[4] = {ns4.x, ns4.y, ns4.z, ns4.w};
#pragma unroll
      for (int rf = 0; rf < 4; ++rf) {
        ushort4 u;
        float s = 0.f;
        unsigned short uu;
        uu = f2bf(__expf(p[nf][rf][0] - nsa[0]) * 0.0625f); u.x = uu; s += bf2f(uu);
        uu = f2bf(__expf(p[nf][rf][1] - nsa[1]) * 0.0625f); u.y = uu; s += bf2f(uu);
        uu = f2bf(__expf(p[nf][rf][2] - nsa[2]) * 0.0625f); u.z = uu; s += bf2f(uu);
        uu = f2bf(__expf(p[nf][rf][3] - nsa[3]) * 0.0625f); u.w = uu; s += bf2f(uu);
        dacc[rf] += s;
        *(ushort4*)&phL[wv * 64 + rf * 16 + lr][nf * 16 + lg * 4] = u;
      }
    }
    {
      short8v af[4], bf_[4];
#pragma unroll
      for (int rf = 0; rf < 4; ++rf)
        af[rf] = *(const short8v*)&phL[wv * 64 + rf * 16 + lr][lg * 8];
#pragma unroll
      for (int df = 0; df < 4; ++df)
        bf_[df] = *(const short8v*)&vT[df * 16 + lr][lg * 8];
#pragma unroll
      for (int rf = 0; rf < 4; ++rf)
#pragma unroll
        for (int df = 0; df < 4; ++df)
          acc[rf][df] = __builtin_amdgcn_mfma_f32_16x16x32_bf16(
              af[rf], bf_[df], acc[rf][df], 0, 0, 0);
    }
  }
  size_t rbase = (((size_t)gb * 16 + nc) * 16 + h) * 256;
#pragma unroll
  for (int rf = 0; rf < 4; ++rf) {
#pragma unroll
    for (int df = 0; df < 4; ++df)
#pragma unroll
      for (int i = 0; i < 4; ++i) {
        int r = wv * 64 + rf * 16 + lg * 4 + i;
        kvp[(rbase + r) * 64 + df * 16 + lr] = f2bf(acc[rf][df][i]);
      }
    float dv2 = dacc[rf];
    dv2 += __shfl_xor(dv2, 16);
    dv2 += __shfl_xor(dv2, 32);
    if (lg == 0) dpart[rbase + wv * 64 + rf * 16 + lr] = dv2;
  }
}

// ---------------- reduce bf16 partials -> KV^T bf16 + denv, batched z
__global__ __launch_bounds__(256) void k_reduce_t(
    const unsigned short* __restrict__ kvp, const float* __restrict__ dpart,
    unsigned short* __restrict__ kvt, float* __restrict__ denv) {
  __shared__ __align__(16) float tile[32][69];
  const int rb = blockIdx.x, h = blockIdx.y, gb = blockIdx.z;
  const int t = threadIdx.x;
  const int rl = t >> 3, sd = (t & 7) * 8;
  float s[8] = {};
  for (int c = 0; c < 16; ++c) {
    const unsigned short* p = kvp +
        ((((size_t)gb * 16 + c) * 16 + h) * 256 + rb * 32 + rl) * 64 + sd;
    short8v b8 = *(const short8v*)p;
#pragma unroll
    for (int j = 0; j < 8; ++j) s[j] += bf2f((unsigned short)b8[j]);
  }
#pragma unroll
  for (int j = 0; j < 8; ++j) tile[rl][sd + j] = s[j];
  __syncthreads();
  int d = t >> 2, rj = (t & 3) * 8;
  short8v u;
#pragma unroll
  for (int j = 0; j < 8; ++j) u[j] = (short)f2bf(tile[rj + j][d]);
  *(short8v*)&kvt[(((size_t)gb * 16 + h) * 64 + d) * 256 + rb * 32 + rj] = u;
  if (rb == 0) {
    float sum = 0.f;
    for (int c = 0; c < 16; ++c)
      sum += dpart[(((size_t)gb * 16 + c) * 16 + h) * 256 + t];
    denv[((size_t)gb * 16 + h) * 256 + t] = sum;
  }
}

// ---------------- pass B: phi_q (split MFMA, gload_lds-staged) + PV MFMA
__global__ __launch_bounds__(256) void k_pass_b_mfma(
    const unsigned short* __restrict__ qhi_g,
    const unsigned short* __restrict__ qlo_g, const float* __restrict__ nsqq,
    const unsigned short* __restrict__ wrmh,
    const unsigned short* __restrict__ wrml,
    const unsigned short* __restrict__ kvt, const float* __restrict__ denv,
    unsigned short* __restrict__ attnb) {
  __shared__ __align__(16) unsigned short kvL[64][264];
  __shared__ __align__(16) unsigned short phL[32][264];
  __shared__ __align__(16) unsigned short sQhi[2048];
  __shared__ __align__(16) unsigned short sQlo[2048];
  __shared__ __align__(16) unsigned short outL[32][80];
  __shared__ __align__(16) float denvL[256];
  __shared__ __align__(16) float nsL[32];
  __shared__ float denp[4][32];
  __shared__ float invL[32];
  const int t = threadIdx.x;
  const int lane = t & 63, wv = t >> 6;
  const int lr = lane & 15, lg = lane >> 4;
  const int nc = blockIdx.x, h = blockIdx.y, gb = blockIdx.z;
  const unsigned short* qbh = qhi_g + ((size_t)gb * 16 + h) * 262144;
  const unsigned short* qbl = qlo_g + ((size_t)gb * 16 + h) * 262144;
  const float* nsb = nsqq + ((size_t)gb * 16 + h) * 4096;
  unsigned short* ao = attnb + (size_t)gb * 4194304;
  {
    const unsigned short* src =
        kvt + ((size_t)gb * 16 + h) * 16384 + (size_t)t * 64;
    int d = t >> 2, r0 = (t & 3) * 64;
#pragma unroll
    for (int j = 0; j < 8; ++j)
      *(short8v*)&kvL[d][r0 + j * 8] = *(const short8v*)(src + j * 8);
    denvL[t] = denv[((size_t)gb * 16 + h) * 256 + t];
  }
  for (int tile = 0; tile < 4; ++tile) {
    const int n0 = nc * 128 + tile * 32;
    __syncthreads();
    stage_tile32(qbh + (size_t)n0 * 64, sQhi, t);
    stage_tile32(qbl + (size_t)n0 * 64, sQlo, t);
    if (t < 32) nsL[t] = nsb[n0 + t];
    asm volatile("s_waitcnt vmcnt(0)");
    __syncthreads();
    float4v p[4][2];
#pragma unroll
    for (int a = 0; a < 4; ++a)
#pragma unroll
      for (int b = 0; b < 2; ++b) p[a][b] = (float4v){0.f, 0.f, 0.f, 0.f};
#pragma unroll
    for (int ks = 0; ks < 2; ++ks) {
      short8v bh[2], bl[2];
#pragma unroll
      for (int nf = 0; nf < 2; ++nf) {
        bh[nf] = read_frag(sQhi, nf * 16 + lr, ks * 4 + lg);
        bl[nf] = read_frag(sQlo, nf * 16 + lr, ks * 4 + lg);
      }
#pragma unroll
      for (int rf = 0; rf < 4; ++rf) {
        size_t wo = (size_t)(wv * 64 + rf * 16 + lr) * 64 + ks * 32 + lg * 8;
        short8v ah = *(const short8v*)&wrmh[wo];
        short8v al = *(const short8v*)&wrml[wo];
#pragma unroll
        for (int nf = 0; nf < 2; ++nf) {
          p[rf][nf] = __builtin_amdgcn_mfma_f32_16x16x32_bf16(ah, bh[nf], p[rf][nf], 0, 0, 0);
          p[rf][nf] = __builtin_amdgcn_mfma_f32_16x16x32_bf16(al, bh[nf], p[rf][nf], 0, 0, 0);
          p[rf][nf] = __builtin_amdgcn_mfma_f32_16x16x32_bf16(ah, bl[nf], p[rf][nf], 0, 0, 0);
        }
      }
    }
    float dnp[2] = {0.f, 0.f};
#pragma unroll
    for (int nf = 0; nf < 2; ++nf) {
      float ns = nsL[nf * 16 + lr];
#pragma unroll
      for (int rf = 0; rf < 4; ++rf) {
        float4 dv4 = *(const float4*)&denvL[wv * 64 + rf * 16 + lg * 4];
        float da[4] = {dv4.x, dv4.y, dv4.z, dv4.w};
        ushort4 u;
        unsigned short uu;
        float s = 0.f;
        uu = f2bf(__expf(p[rf][nf][0] - ns) * 0.0625f); u.x = uu; s += bf2f(uu) * da[0];
        uu = f2bf(__expf(p[rf][nf][1] - ns) * 0.0625f); u.y = uu; s += bf2f(uu) * da[1];
        uu = f2bf(__expf(p[rf][nf][2] - ns) * 0.0625f); u.z = uu; s += bf2f(uu) * da[2];
        uu = f2bf(__expf(p[rf][nf][3] - ns) * 0.0625f); u.w = uu; s += bf2f(uu) * da[3];
        dnp[nf] += s;
        *(ushort4*)&phL[nf * 16 + lr][wv * 64 + rf * 16 + lg * 4] = u;
      }
    }
#pragma unroll
    for (int nf = 0; nf < 2; ++nf) {
      float v2 = dnp[nf];
      v2 += __shfl_xor(v2, 16);
      v2 += __shfl_xor(v2, 32);
      if (lg == 0) denp[wv][nf * 16 + lr] = v2;
    }
    __syncthreads();
    if (t < 32) {
      float dn = denp[0][t] + denp[1][t] + denp[2][t] + denp[3][t];
      invL[t] = 1.0f / (dn + 1e-6f);
    }
    __syncthreads();
    const int nfj = wv & 1;
    float4v o[2];
    o[0] = (float4v){0.f, 0.f, 0.f, 0.f};
    o[1] = (float4v){0.f, 0.f, 0.f, 0.f};
#pragma unroll
    for (int ks = 0; ks < 8; ++ks) {
      short8v af = *(const short8v*)&phL[nfj * 16 + lr][ks * 32 + lg * 8];
#pragma unroll
      for (int j = 0; j < 2; ++j) {
        int df = (wv >> 1) * 2 + j;
        short8v bfr = *(const short8v*)&kvL[df * 16 + lr][ks * 32 + lg * 8];
        o[j] = __builtin_amdgcn_mfma_f32_16x16x32_bf16(af, bfr, o[j], 0, 0, 0);
      }
    }
#pragma unroll
    for (int j = 0; j < 2; ++j) {
      int df = (wv >> 1) * 2 + j;
#pragma unroll
      for (int i = 0; i < 4; ++i) {
        int n = nfj * 16 + lg * 4 + i;
        outL[n][df * 16 + lr] = f2bf(o[j][i] * invL[n]);
      }
    }
    __syncthreads();
    {
      int sn = t >> 3, sd = (t & 7) * 8;
      short8v v8 = *(const short8v*)&outL[sn][sd];
      *(short8v*)&ao[((size_t)(n0 + sn)) * 1024 + h * 64 + sd] = v8;
    }
  }
}

// ---------------- out GEMM: XCD remap + LDS-staged full-line writes (verified)
__global__ __launch_bounds__(256, 2) void k_out_mfma(
    const unsigned short* __restrict__ ab, const unsigned short* __restrict__ wp,
    const float* __restrict__ bp, float* __restrict__ out) {
  __shared__ unsigned short ldsA[8192];
  __shared__ unsigned short ldsB[8192];
  __shared__ __align__(16) float foutS[64][132];
  const int t = threadIdx.x;
  const int lane = t & 63, wv = t >> 6;
  const int wm = wv >> 1, wn = wv & 1;
  const int lr = lane & 15, lg = lane >> 4;
  const int flat = blockIdx.y * 8 + blockIdx.x;       // grid (8,128)
  const int mBase = (flat & 127) * 128;
  const int jBase = (flat >> 7) * 128;
  float4v acc[4][4];
#pragma unroll
  for (int a = 0; a < 4; ++a)
#pragma unroll
    for (int b = 0; b < 4; ++b) acc[a][b] = (float4v){0.f, 0.f, 0.f, 0.f};

  for (int kt = 0; kt < 1024; kt += 64) {
    __syncthreads();
    stage_tile(ab + (size_t)mBase * 1024 + kt, ldsA, t);
    stage_tile(wp + (size_t)jBase * 1024 + kt, ldsB, t);
    asm volatile("s_waitcnt vmcnt(0)");
    __syncthreads();
#pragma unroll
    for (int ks = 0; ks < 2; ++ks) {
      const int seg = ks * 4 + lg;
      short8v a[4], b[4];
#pragma unroll
      for (int f = 0; f < 4; ++f) {
        a[f] = read_frag(ldsA, wm * 64 + f * 16 + lr, seg);
        b[f] = read_frag(ldsB, wn * 64 + f * 16 + lr, seg);
      }
#pragma unroll
      for (int fm = 0; fm < 4; ++fm)
#pragma unroll
        for (int fn = 0; fn < 4; ++fn)
          acc[fm][fn] = __builtin_amdgcn_mfma_f32_16x16x32_bf16(
              a[fm], b[fn], acc[fm][fn], 0, 0, 0);
    }
  }
  float biasv[4];
#pragma unroll
  for (int fn = 0; fn < 4; ++fn)
    biasv[fn] = bp[jBase + wn * 64 + fn * 16 + lr];
#pragma unroll
  for (int ph = 0; ph < 2; ++ph) {
    __syncthreads();
    if (wm == ph) {
#pragma unroll
      for (int fm = 0; fm < 4; ++fm)
#pragma unroll
        for (int fn = 0; fn < 4; ++fn)
#pragma unroll
          for (int r = 0; r < 4; ++r)
            foutS[fm * 16 + lg * 4 + r][wn * 64 + fn * 16 + lr] =
                acc[fm][fn][r] + biasv[fn];
    }
    __syncthreads();
#pragma unroll
    for (int i = 0; i < 8; ++i) {
      int row = i * 8 + (t >> 5);
      int c0 = (t & 31) * 4;
      *(float4*)&out[(size_t)(mBase + ph * 64 + row) * 1024 + jBase + c0] =
          *(const float4*)&foutS[row][c0];
    }
  }
}

}  // namespace

extern "C" void kernel_launch(void* const* d_in, const int* in_sizes, int n_in,
                              void* d_out, int out_size, void* d_ws,
                              size_t ws_size, hipStream_t stream) {
  const float *x = nullptr, *Wqkv = nullptr, *bqkv = nullptr;
  const float *Wproj = nullptr, *bproj = nullptr, *Wrm = nullptr;
  for (int i = 0; i < n_in; ++i) {
    switch (in_sizes[i]) {
      case 16777216: x     = (const float*)d_in[i]; break;
      case 3145728:  Wqkv  = (const float*)d_in[i]; break;
      case 3072:     bqkv  = (const float*)d_in[i]; break;
      case 1048576:  Wproj = (const float*)d_in[i]; break;
      case 1024:     bproj = (const float*)d_in[i]; break;
      case 16384:    Wrm   = (const float*)d_in[i]; break;
      default: break;
    }
  }
  float* out = (float*)d_out;
  float* ws = (float*)d_ws;

  if (!x || !Wqkv || !bqkv || !Wproj || !bproj || !Wrm) {
    k_sent<<<1, 1, 0, stream>>>(out, 2000.0f);
    return;
  }
  if (ws_size < WS_ELEMS * sizeof(float)) {
    k_sent<<<1, 1, 0, stream>>>(out, 1000.0f);
    return;
  }

  unsigned short* qhi  = (unsigned short*)(ws + QHI_OFF);
  unsigned short* qlo  = (unsigned short*)(ws + QLO_OFF);
  unsigned short* khi  = (unsigned short*)(ws + KHI_OFF);
  unsigned short* klo  = (unsigned short*)(ws + KLO_OFF);
  unsigned short* vb   = (unsigned short*)(ws + V_OFF);
  unsigned short* xh   = (unsigned short*)(ws + XH_OFF);
  unsigned short* kvp  = (unsigned short*)(ws + KVP_OFF);
  unsigned short* kvt  = (unsigned short*)(ws + KVT_OFF);
  unsigned short* ambf = (unsigned short*)(ws + ATTNB_OFF);
  unsigned short* wh   = (unsigned short*)(ws + WH_OFF);
  unsigned short* wl   = (unsigned short*)(ws + WL_OFF);
  unsigned short* wrmh = (unsigned short*)(ws + WRMH_OFF);
  unsigned short* wrml = (unsigned short*)(ws + WRML_OFF);
  unsigned short* wph  = (unsigned short*)(ws + WPH_OFF);

  // conversions (once, all batches)
  k_conv_split<<<3072, 256, 0, stream>>>(Wqkv, wh, wl, 786432);
  k_conv_split<<<16, 256, 0, stream>>>(Wrm, wrmh, wrml, 4096);
  k_conv_hi<<<1024, 256, 0, stream>>>(Wproj, wph, 262144);
  k_conv_hi<<<16384, 256, 0, stream>>>(x, xh, 4194304);

  // all-batch fused pipeline
  k_qkv_mfma<<<dim3(16, 128), 256, 0, stream>>>(xh, wh, wl, bqkv, qhi, qlo,
                                                khi, klo, ws + NSQQ_OFF,
                                                ws + NSQK_OFF);
  k_qkv_v<<<dim3(8, 128), 256, 0, stream>>>(xh, wh, bqkv, vb);
  k_pass_a_mfma<<<dim3(16, 16, 4), 256, 0, stream>>>(khi, klo, ws + NSQK_OFF,
                                                     vb, wrmh, wrml, kvp,
                                                     ws + DPART_OFF);
  k_reduce_t<<<dim3(8, 16, 4), 256, 0, stream>>>(kvp, ws + DPART_OFF, kvt,
                                                 ws + DENV_OFF);
  k_pass_b_mfma<<<dim3(32, 16, 4), 256, 0, stream>>>(qhi, qlo, ws + NSQQ_OFF,
                                                     wrmh, wrml, kvt,
                                                     ws + DENV_OFF, ambf);
  k_out_mfma<<<dim3(8, 128), 256, 0, stream>>>(ambf, wph, bproj, out);
}

// Round 13
// 370.286 us; speedup vs baseline: 1.1338x; 1.1338x over previous
//
#include <hip/hip_runtime.h>
#include <hip/hip_bf16.h>

namespace {

typedef __attribute__((ext_vector_type(8))) short short8v;   // 8 bf16
typedef __attribute__((ext_vector_type(4))) float float4v;   // 4 f32

// ---- workspace layout (float-slot offsets), ALL-BATCH fused (r10 proven) ----
constexpr size_t QB1      = 4194304;                 // 16h*4096*64 per batch
constexpr size_t Q_OFF    = 0;                       // f32 [4][16h][4096][64]
constexpr size_t K_OFF    = 16777216;                // f32 [4][16h][4096][64]
constexpr size_t ATTNB_OFF = K_OFF;                  // ushort overlay (K dead)
constexpr size_t V_OFF    = 33554432;                // ushort [4][16h][4096][64]
constexpr size_t XH_OFF   = 41943040;                // ushort [16384][1024]
constexpr size_t KVP_OFF  = XH_OFF;                  // ushort overlay (xh dead)
constexpr size_t DPART_OFF = 50331648;               // f32 [4][16nc][16h][256]
constexpr size_t KVT_OFF  = DPART_OFF + 262144;      // ushort [4][16h][64][256]
constexpr size_t DENV_OFF = KVT_OFF + 524288;        // f32 [4][16h][256]
constexpr size_t WH_OFF   = DENV_OFF + 16384;        // ushort Wqkv hi
constexpr size_t WL_OFF   = WH_OFF + 1572864;        // ushort Wqkv lo
constexpr size_t WRMH_OFF = WL_OFF + 1572864;        // ushort Wrm hi
constexpr size_t WRML_OFF = WRMH_OFF + 8192;
constexpr size_t WPH_OFF  = WRML_OFF + 8192;         // ushort Wproj hi
constexpr size_t WS_ELEMS = WPH_OFF + 524288;        // 54,820,864 (~219.3 MB)

__device__ __forceinline__ unsigned short f2bf(float f) {
  unsigned int u = __float_as_uint(f);
  u += 0x7FFFu + ((u >> 16) & 1u);                   // round-to-nearest-even
  return (unsigned short)(u >> 16);
}
__device__ __forceinline__ float bf2f(unsigned short u) {
  return __uint_as_float((unsigned)u << 16);
}

__global__ void k_sent(float* out, float v) { out[0] = v; }

// ---------------- fp32 -> bf16 hi+lo split (weights)
__global__ __launch_bounds__(256) void k_conv_split(
    const float* __restrict__ src, unsigned short* __restrict__ hi,
    unsigned short* __restrict__ lo, int n4) {
  int i = blockIdx.x * 256 + threadIdx.x;
  if (i >= n4) return;
  float4 v = *(const float4*)&src[(size_t)i * 4];
  ushort4 h, l;
  h.x = f2bf(v.x); l.x = f2bf(v.x - bf2f(h.x));
  h.y = f2bf(v.y); l.y = f2bf(v.y - bf2f(h.y));
  h.z = f2bf(v.z); l.z = f2bf(v.z - bf2f(h.z));
  h.w = f2bf(v.w); l.w = f2bf(v.w - bf2f(h.w));
  *(ushort4*)&hi[(size_t)i * 4] = h;
  *(ushort4*)&lo[(size_t)i * 4] = l;
}

__global__ __launch_bounds__(256) void k_conv_hi(
    const float* __restrict__ src, unsigned short* __restrict__ hi, int n4) {
  int i = blockIdx.x * 256 + threadIdx.x;
  if (i >= n4) return;
  float4 v = *(const float4*)&src[(size_t)i * 4];
  ushort4 h = {f2bf(v.x), f2bf(v.y), f2bf(v.z), f2bf(v.w)};
  *(ushort4*)&hi[(size_t)i * 4] = h;
}

// ---- stage [128 rows][64 k] bf16 tile via global_load_lds (verified) ----
__device__ __forceinline__ void stage_tile(const unsigned short* __restrict__ src,
                                           unsigned short* __restrict__ dst,
                                           int t) {
#pragma unroll
  for (int i = 0; i < 4; ++i) {
    int c = i * 256 + t;
    int row = c >> 3;
    int seg = (c & 7) ^ (row & 7);
    __builtin_amdgcn_global_load_lds(
        (const __attribute__((address_space(1))) void*)(src + (size_t)row * 1024 + seg * 8),
        (__attribute__((address_space(3))) void*)(dst + (size_t)c * 8),
        16, 0, 0);
  }
}

__device__ __forceinline__ short8v read_frag(const unsigned short* lds, int row,
                                             int seg) {
  return *(const short8v*)&lds[(size_t)row * 64 + ((seg ^ (row & 7)) * 8)];
}

// ---------------- merged qkv GEMM (all batches, all 24 j-tiles):
//   bx<16: q/k columns, 2-MFMA split (xh@wh + xh@wl) -> fp32 q/k
//   bx>=16: v columns, plain bf16 1-MFMA -> bf16 v
__global__ __launch_bounds__(256, 2) void k_qkv_all(
    const unsigned short* __restrict__ xh,
    const unsigned short* __restrict__ wh, const unsigned short* __restrict__ wl,
    const float* __restrict__ bq, float* __restrict__ ws,
    unsigned short* __restrict__ vb) {
  __shared__ unsigned short ldsA[8192];
  __shared__ unsigned short ldsB[2][8192];
  const int t = threadIdx.x;
  const int lane = t & 63, wv = t >> 6;
  const int wm = wv >> 1, wn = wv & 1;
  const int lr = lane & 15, lg = lane >> 4;
  const int bx = blockIdx.x;                    // 0..23
  const int mBase = blockIdx.y * 128;           // global row
  const bool isv = bx >= 16;
  const int jBase = isv ? 2048 + (bx - 16) * 128 : bx * 128;
  const int gb = mBase >> 12;
  const int nn0 = mBase & 4095;
  float4v acc[4][4];
#pragma unroll
  for (int a = 0; a < 4; ++a)
#pragma unroll
    for (int b = 0; b < 4; ++b) acc[a][b] = (float4v){0.f, 0.f, 0.f, 0.f};

  for (int kt = 0; kt < 1024; kt += 64) {
    __syncthreads();
    stage_tile(xh + (size_t)mBase * 1024 + kt, ldsA, t);
    stage_tile(wh + (size_t)jBase * 1024 + kt, ldsB[0], t);
    if (!isv) stage_tile(wl + (size_t)jBase * 1024 + kt, ldsB[1], t);
    asm volatile("s_waitcnt vmcnt(0)");
    __syncthreads();
    if (!isv) {
#pragma unroll
      for (int ks = 0; ks < 2; ++ks) {
        const int seg = ks * 4 + lg;
        short8v ah[4], bh[4], bl[4];
#pragma unroll
        for (int f = 0; f < 4; ++f) {
          ah[f] = read_frag(ldsA, wm * 64 + f * 16 + lr, seg);
          int rb = wn * 64 + f * 16 + lr;
          bh[f] = read_frag(ldsB[0], rb, seg);
          bl[f] = read_frag(ldsB[1], rb, seg);
        }
#pragma unroll
        for (int fm = 0; fm < 4; ++fm)
#pragma unroll
          for (int fn = 0; fn < 4; ++fn) {
            acc[fm][fn] = __builtin_amdgcn_mfma_f32_16x16x32_bf16(
                ah[fm], bh[fn], acc[fm][fn], 0, 0, 0);
            acc[fm][fn] = __builtin_amdgcn_mfma_f32_16x16x32_bf16(
                ah[fm], bl[fn], acc[fm][fn], 0, 0, 0);
          }
      }
    } else {
#pragma unroll
      for (int ks = 0; ks < 2; ++ks) {
        const int seg = ks * 4 + lg;
        short8v a[4], b[4];
#pragma unroll
        for (int f = 0; f < 4; ++f) {
          a[f] = read_frag(ldsA, wm * 64 + f * 16 + lr, seg);
          b[f] = read_frag(ldsB[0], wn * 64 + f * 16 + lr, seg);
        }
#pragma unroll
        for (int fm = 0; fm < 4; ++fm)
#pragma unroll
          for (int fn = 0; fn < 4; ++fn)
            acc[fm][fn] = __builtin_amdgcn_mfma_f32_16x16x32_bf16(
                a[fm], b[fn], acc[fm][fn], 0, 0, 0);
      }
    }
  }
  if (!isv) {
    // q/k epilogue: fp32 writes (r10 verbatim)
    const int t3 = jBase >> 10;                       // 0=q, 1=k
#pragma unroll
    for (int fn = 0; fn < 4; ++fn) {
      int j = jBase + wn * 64 + fn * 16 + lr;
      int h = (j >> 6) & 15, dd = j & 63;
      float bias = bq[j];
      float* op = ws + (t3 ? K_OFF : Q_OFF) + (size_t)gb * QB1 +
                  (size_t)h * 262144 + dd;
#pragma unroll
      for (int fm = 0; fm < 4; ++fm) {
        int n0 = nn0 + wm * 64 + fm * 16 + lg * 4;
#pragma unroll
        for (int r = 0; r < 4; ++r)
          op[(size_t)(n0 + r) * 64] = acc[fm][fn][r] + bias;
      }
    }
  } else {
    // v epilogue: bf16 writes (r10 verbatim)
#pragma unroll
    for (int fn = 0; fn < 4; ++fn) {
      int j = jBase + wn * 64 + fn * 16 + lr;
      int h = (j >> 6) & 15, dd = j & 63;
      float bias = bq[j];
      unsigned short* op = vb + (size_t)gb * 4194304 + (size_t)h * 262144 + dd;
#pragma unroll
      for (int fm = 0; fm < 4; ++fm) {
        int n0 = nn0 + wm * 64 + fm * 16 + lg * 4;
#pragma unroll
        for (int r = 0; r < 4; ++r)
          op[(size_t)(n0 + r) * 64] = f2bf(acc[fm][fn][r] + bias);
      }
    }
  }
}

// ---------------- pass A: fused phi_k (split MFMA) + KV MFMA, batched z (r10)
__global__ __launch_bounds__(256) void k_pass_a_mfma(
    const float* __restrict__ ws, const unsigned short* __restrict__ vbb,
    const unsigned short* __restrict__ wrmh,
    const unsigned short* __restrict__ wrml, unsigned short* __restrict__ kvp,
    float* __restrict__ dpart) {
  __shared__ __align__(16) unsigned short khi[32][72];
  __shared__ __align__(16) unsigned short klo[32][72];
  __shared__ __align__(16) unsigned short vT[64][40];
  __shared__ __align__(16) unsigned short phL[256][40];
  __shared__ __align__(16) float nsL[32];
  const int t = threadIdx.x;
  const int lane = t & 63, wv = t >> 6;
  const int lr = lane & 15, lg = lane >> 4;
  const int nc = blockIdx.x, h = blockIdx.y, gb = blockIdx.z;
  const float* kb = ws + K_OFF + (size_t)gb * QB1 + (size_t)h * 262144;
  const unsigned short* vbh = vbb + (size_t)gb * 4194304 + (size_t)h * 262144;
  float4v acc[4][4];
#pragma unroll
  for (int a = 0; a < 4; ++a)
#pragma unroll
    for (int b = 0; b < 4; ++b) acc[a][b] = (float4v){0.f, 0.f, 0.f, 0.f};
  float dacc[4] = {};

  for (int tile = 0; tile < 8; ++tile) {
    const int n0 = nc * 256 + tile * 32;
    __syncthreads();
    {  // stage k hi/lo + ns
      int sn = t >> 3, sd = (t & 7) * 8;
      const float* kp = kb + (size_t)(n0 + sn) * 64 + sd;
      float4 a0 = *(const float4*)kp;
      float4 a1 = *(const float4*)(kp + 4);
      float vv[8] = {a0.x, a0.y, a0.z, a0.w, a1.x, a1.y, a1.z, a1.w};
      short8v hv, lv;
      float ss = 0.f;
#pragma unroll
      for (int j = 0; j < 8; ++j) {
        ss += vv[j] * vv[j];
        unsigned short hu = f2bf(vv[j]);
        hv[j] = (short)hu;
        lv[j] = (short)f2bf(vv[j] - bf2f(hu));
      }
      *(short8v*)&khi[sn][sd] = hv;
      *(short8v*)&klo[sn][sd] = lv;
      ss += __shfl_xor(ss, 1); ss += __shfl_xor(ss, 2); ss += __shfl_xor(ss, 4);
      if ((t & 7) == 0) nsL[sn] = 0.5f * ss;
    }
    {  // stage v (bf16) transposed
      int sn = t & 31, sd = (t >> 5) * 8;
      short8v v8 = *(const short8v*)&vbh[(size_t)(n0 + sn) * 64 + sd];
#pragma unroll
      for (int j = 0; j < 8; ++j) vT[sd + j][sn] = (unsigned short)v8[j];
    }
    __syncthreads();
    float4v p[2][4];
#pragma unroll
    for (int a = 0; a < 2; ++a)
#pragma unroll
      for (int b = 0; b < 4; ++b) p[a][b] = (float4v){0.f, 0.f, 0.f, 0.f};
#pragma unroll
    for (int ks = 0; ks < 2; ++ks) {
      short8v ah[2], al[2];
#pragma unroll
      for (int nf = 0; nf < 2; ++nf) {
        ah[nf] = *(const short8v*)&khi[nf * 16 + lr][ks * 32 + lg * 8];
        al[nf] = *(const short8v*)&klo[nf * 16 + lr][ks * 32 + lg * 8];
      }
#pragma unroll
      for (int rf = 0; rf < 4; ++rf) {
        size_t wo = (size_t)(wv * 64 + rf * 16 + lr) * 64 + ks * 32 + lg * 8;
        short8v bh = *(const short8v*)&wrmh[wo];
        short8v bl = *(const short8v*)&wrml[wo];
#pragma unroll
        for (int nf = 0; nf < 2; ++nf) {
          p[nf][rf] = __builtin_amdgcn_mfma_f32_16x16x32_bf16(ah[nf], bh, p[nf][rf], 0, 0, 0);
          p[nf][rf] = __builtin_amdgcn_mfma_f32_16x16x32_bf16(ah[nf], bl, p[nf][rf], 0, 0, 0);
          p[nf][rf] = __builtin_amdgcn_mfma_f32_16x16x32_bf16(al[nf], bh, p[nf][rf], 0, 0, 0);
        }
      }
    }
#pragma unroll
    for (int nf = 0; nf < 2; ++nf) {
      float4 ns4 = *(const float4*)&nsL[nf * 16 + lg * 4];
      float nsa[4] = {ns4.x, ns4.y, ns4.z, ns4.w};
#pragma unroll
      for (int rf = 0; rf < 4; ++rf) {
        ushort4 u;
        float s = 0.f;
        unsigned short uu;
        uu = f2bf(__expf(p[nf][rf][0] - nsa[0]) * 0.0625f); u.x = uu; s += bf2f(uu);
        uu = f2bf(__expf(p[nf][rf][1] - nsa[1]) * 0.0625f); u.y = uu; s += bf2f(uu);
        uu = f2bf(__expf(p[nf][rf][2] - nsa[2]) * 0.0625f); u.z = uu; s += bf2f(uu);
        uu = f2bf(__expf(p[nf][rf][3] - nsa[3]) * 0.0625f); u.w = uu; s += bf2f(uu);
        dacc[rf] += s;
        *(ushort4*)&phL[wv * 64 + rf * 16 + lr][nf * 16 + lg * 4] = u;
      }
    }
    {
      short8v af[4], bf_[4];
#pragma unroll
      for (int rf = 0; rf < 4; ++rf)
        af[rf] = *(const short8v*)&phL[wv * 64 + rf * 16 + lr][lg * 8];
#pragma unroll
      for (int df = 0; df < 4; ++df)
        bf_[df] = *(const short8v*)&vT[df * 16 + lr][lg * 8];
#pragma unroll
      for (int rf = 0; rf < 4; ++rf)
#pragma unroll
        for (int df = 0; df < 4; ++df)
          acc[rf][df] = __builtin_amdgcn_mfma_f32_16x16x32_bf16(
              af[rf], bf_[df], acc[rf][df], 0, 0, 0);
    }
  }
  size_t rbase = (((size_t)gb * 16 + nc) * 16 + h) * 256;
#pragma unroll
  for (int rf = 0; rf < 4; ++rf) {
#pragma unroll
    for (int df = 0; df < 4; ++df)
#pragma unroll
      for (int i = 0; i < 4; ++i) {
        int r = wv * 64 + rf * 16 + lg * 4 + i;
        kvp[(rbase + r) * 64 + df * 16 + lr] = f2bf(acc[rf][df][i]);
      }
    float dv2 = dacc[rf];
    dv2 += __shfl_xor(dv2, 16);
    dv2 += __shfl_xor(dv2, 32);
    if (lg == 0) dpart[rbase + wv * 64 + rf * 16 + lr] = dv2;
  }
}

// ---------------- reduce bf16 partials -> KV^T bf16 + denv, batched z (r10)
__global__ __launch_bounds__(256) void k_reduce_t(
    const unsigned short* __restrict__ kvp, const float* __restrict__ dpart,
    unsigned short* __restrict__ kvt, float* __restrict__ denv) {
  __shared__ __align__(16) float tile[32][69];
  const int rb = blockIdx.x, h = blockIdx.y, gb = blockIdx.z;
  const int t = threadIdx.x;
  const int rl = t >> 3, sd = (t & 7) * 8;
  float s[8] = {};
  for (int c = 0; c < 16; ++c) {
    const unsigned short* p = kvp +
        ((((size_t)gb * 16 + c) * 16 + h) * 256 + rb * 32 + rl) * 64 + sd;
    short8v b8 = *(const short8v*)p;
#pragma unroll
    for (int j = 0; j < 8; ++j) s[j] += bf2f((unsigned short)b8[j]);
  }
#pragma unroll
  for (int j = 0; j < 8; ++j) tile[rl][sd + j] = s[j];
  __syncthreads();
  int d = t >> 2, rj = (t & 3) * 8;
  short8v u;
#pragma unroll
  for (int j = 0; j < 8; ++j) u[j] = (short)f2bf(tile[rj + j][d]);
  *(short8v*)&kvt[(((size_t)gb * 16 + h) * 64 + d) * 256 + rb * 32 + rj] = u;
  if (rb == 0) {
    float sum = 0.f;
    for (int c = 0; c < 16; ++c)
      sum += dpart[(((size_t)gb * 16 + c) * 16 + h) * 256 + t];
    denv[((size_t)gb * 16 + h) * 256 + t] = sum;
  }
}

// ---------------- pass B: fused phi_q (split MFMA) + PV MFMA, batched z (r10)
__global__ __launch_bounds__(256) void k_pass_b_mfma(
    const float* __restrict__ ws, const unsigned short* __restrict__ wrmh,
    const unsigned short* __restrict__ wrml,
    const unsigned short* __restrict__ kvt, const float* __restrict__ denv,
    unsigned short* __restrict__ attnb) {
  __shared__ __align__(16) unsigned short kvL[64][264];
  __shared__ __align__(16) unsigned short phL[32][264];
  __shared__ __align__(16) unsigned short qhi[32][72];
  __shared__ __align__(16) unsigned short qlo[32][72];
  __shared__ __align__(16) unsigned short outL[32][80];
  __shared__ __align__(16) float denvL[256];
  __shared__ __align__(16) float nsL[32];
  __shared__ float denp[4][32];
  __shared__ float invL[32];
  const int t = threadIdx.x;
  const int lane = t & 63, wv = t >> 6;
  const int lr = lane & 15, lg = lane >> 4;
  const int nc = blockIdx.x, h = blockIdx.y, gb = blockIdx.z;
  const float* qb = ws + Q_OFF + (size_t)gb * QB1 + (size_t)h * 262144;
  unsigned short* ao = attnb + (size_t)gb * 4194304;
  {
    const unsigned short* src =
        kvt + ((size_t)gb * 16 + h) * 16384 + (size_t)t * 64;
    int d = t >> 2, r0 = (t & 3) * 64;
#pragma unroll
    for (int j = 0; j < 8; ++j)
      *(short8v*)&kvL[d][r0 + j * 8] = *(const short8v*)(src + j * 8);
    denvL[t] = denv[((size_t)gb * 16 + h) * 256 + t];
  }
  for (int tile = 0; tile < 4; ++tile) {
    const int n0 = nc * 128 + tile * 32;
    __syncthreads();
    {  // stage q hi/lo + ns
      int sn = t >> 3, sd = (t & 7) * 8;
      const float* qp = qb + (size_t)(n0 + sn) * 64 + sd;
      float4 a0 = *(const float4*)qp;
      float4 a1 = *(const float4*)(qp + 4);
      float vv[8] = {a0.x, a0.y, a0.z, a0.w, a1.x, a1.y, a1.z, a1.w};
      short8v hv, lv;
      float ss = 0.f;
#pragma unroll
      for (int j = 0; j < 8; ++j) {
        ss += vv[j] * vv[j];
        unsigned short hu = f2bf(vv[j]);
        hv[j] = (short)hu;
        lv[j] = (short)f2bf(vv[j] - bf2f(hu));
      }
      *(short8v*)&qhi[sn][sd] = hv;
      *(short8v*)&qlo[sn][sd] = lv;
      ss += __shfl_xor(ss, 1); ss += __shfl_xor(ss, 2); ss += __shfl_xor(ss, 4);
      if ((t & 7) == 0) nsL[sn] = 0.5f * ss;
    }
    __syncthreads();
    float4v p[4][2];
#pragma unroll
    for (int a = 0; a < 4; ++a)
#pragma unroll
      for (int b = 0; b < 2; ++b) p[a][b] = (float4v){0.f, 0.f, 0.f, 0.f};
#pragma unroll
    for (int ks = 0; ks < 2; ++ks) {
      short8v bh[2], bl[2];
#pragma unroll
      for (int nf = 0; nf < 2; ++nf) {
        bh[nf] = *(const short8v*)&qhi[nf * 16 + lr][ks * 32 + lg * 8];
        bl[nf] = *(const short8v*)&qlo[nf * 16 + lr][ks * 32 + lg * 8];
      }
#pragma unroll
      for (int rf = 0; rf < 4; ++rf) {
        size_t wo = (size_t)(wv * 64 + rf * 16 + lr) * 64 + ks * 32 + lg * 8;
        short8v ah = *(const short8v*)&wrmh[wo];
        short8v al = *(const short8v*)&wrml[wo];
#pragma unroll
        for (int nf = 0; nf < 2; ++nf) {
          p[rf][nf] = __builtin_amdgcn_mfma_f32_16x16x32_bf16(ah, bh[nf], p[rf][nf], 0, 0, 0);
          p[rf][nf] = __builtin_amdgcn_mfma_f32_16x16x32_bf16(al, bh[nf], p[rf][nf], 0, 0, 0);
          p[rf][nf] = __builtin_amdgcn_mfma_f32_16x16x32_bf16(ah, bl[nf], p[rf][nf], 0, 0, 0);
        }
      }
    }
    float dnp[2] = {0.f, 0.f};
#pragma unroll
    for (int nf = 0; nf < 2; ++nf) {
      float ns = nsL[nf * 16 + lr];
#pragma unroll
      for (int rf = 0; rf < 4; ++rf) {
        float4 dv4 = *(const float4*)&denvL[wv * 64 + rf * 16 + lg * 4];
        float da[4] = {dv4.x, dv4.y, dv4.z, dv4.w};
        ushort4 u;
        unsigned short uu;
        float s = 0.f;
        uu = f2bf(__expf(p[rf][nf][0] - ns) * 0.0625f); u.x = uu; s += bf2f(uu) * da[0];
        uu = f2bf(__expf(p[rf][nf][1] - ns) * 0.0625f); u.y = uu; s += bf2f(uu) * da[1];
        uu = f2bf(__expf(p[rf][nf][2] - ns) * 0.0625f); u.z = uu; s += bf2f(uu) * da[2];
        uu = f2bf(__expf(p[rf][nf][3] - ns) * 0.0625f); u.w = uu; s += bf2f(uu) * da[3];
        dnp[nf] += s;
        *(ushort4*)&phL[nf * 16 + lr][wv * 64 + rf * 16 + lg * 4] = u;
      }
    }
#pragma unroll
    for (int nf = 0; nf < 2; ++nf) {
      float v2 = dnp[nf];
      v2 += __shfl_xor(v2, 16);
      v2 += __shfl_xor(v2, 32);
      if (lg == 0) denp[wv][nf * 16 + lr] = v2;
    }
    __syncthreads();
    if (t < 32) {
      float dn = denp[0][t] + denp[1][t] + denp[2][t] + denp[3][t];
      invL[t] = 1.0f / (dn + 1e-6f);
    }
    __syncthreads();
    const int nfj = wv & 1;
    float4v o[2];
    o[0] = (float4v){0.f, 0.f, 0.f, 0.f};
    o[1] = (float4v){0.f, 0.f, 0.f, 0.f};
#pragma unroll
    for (int ks = 0; ks < 8; ++ks) {
      short8v af = *(const short8v*)&phL[nfj * 16 + lr][ks * 32 + lg * 8];
#pragma unroll
      for (int j = 0; j < 2; ++j) {
        int df = (wv >> 1) * 2 + j;
        short8v bfr = *(const short8v*)&kvL[df * 16 + lr][ks * 32 + lg * 8];
        o[j] = __builtin_amdgcn_mfma_f32_16x16x32_bf16(af, bfr, o[j], 0, 0, 0);
      }
    }
#pragma unroll
    for (int j = 0; j < 2; ++j) {
      int df = (wv >> 1) * 2 + j;
#pragma unroll
      for (int i = 0; i < 4; ++i) {
        int n = nfj * 16 + lg * 4 + i;
        outL[n][df * 16 + lr] = f2bf(o[j][i] * invL[n]);
      }
    }
    __syncthreads();
    {
      int sn = t >> 3, sd = (t & 7) * 8;
      short8v v8 = *(const short8v*)&outL[sn][sd];
      *(short8v*)&ao[((size_t)(n0 + sn)) * 1024 + h * 64 + sd] = v8;
    }
  }
}

// ---------------- out GEMM: XCD remap + LDS-staged full-line writes (r10)
__global__ __launch_bounds__(256, 2) void k_out_mfma(
    const unsigned short* __restrict__ ab, const unsigned short* __restrict__ wp,
    const float* __restrict__ bp, float* __restrict__ out) {
  __shared__ unsigned short ldsA[8192];
  __shared__ unsigned short ldsB[8192];
  __shared__ __align__(16) float foutS[64][132];
  const int t = threadIdx.x;
  const int lane = t & 63, wv = t >> 6;
  const int wm = wv >> 1, wn = wv & 1;
  const int lr = lane & 15, lg = lane >> 4;
  const int flat = blockIdx.y * 8 + blockIdx.x;       // grid (8,128)
  const int mBase = (flat & 127) * 128;
  const int jBase = (flat >> 7) * 128;
  float4v acc[4][4];
#pragma unroll
  for (int a = 0; a < 4; ++a)
#pragma unroll
    for (int b = 0; b < 4; ++b) acc[a][b] = (float4v){0.f, 0.f, 0.f, 0.f};

  for (int kt = 0; kt < 1024; kt += 64) {
    __syncthreads();
    stage_tile(ab + (size_t)mBase * 1024 + kt, ldsA, t);
    stage_tile(wp + (size_t)jBase * 1024 + kt, ldsB, t);
    asm volatile("s_waitcnt vmcnt(0)");
    __syncthreads();
#pragma unroll
    for (int ks = 0; ks < 2; ++ks) {
      const int seg = ks * 4 + lg;
      short8v a[4], b[4];
#pragma unroll
      for (int f = 0; f < 4; ++f) {
        a[f] = read_frag(ldsA, wm * 64 + f * 16 + lr, seg);
        b[f] = read_frag(ldsB, wn * 64 + f * 16 + lr, seg);
      }
#pragma unroll
      for (int fm = 0; fm < 4; ++fm)
#pragma unroll
        for (int fn = 0; fn < 4; ++fn)
          acc[fm][fn] = __builtin_amdgcn_mfma_f32_16x16x32_bf16(
              a[fm], b[fn], acc[fm][fn], 0, 0, 0);
    }
  }
  float biasv[4];
#pragma unroll
  for (int fn = 0; fn < 4; ++fn)
    biasv[fn] = bp[jBase + wn * 64 + fn * 16 + lr];
#pragma unroll
  for (int ph = 0; ph < 2; ++ph) {
    __syncthreads();
    if (wm == ph) {
#pragma unroll
      for (int fm = 0; fm < 4; ++fm)
#pragma unroll
        for (int fn = 0; fn < 4; ++fn)
#pragma unroll
          for (int r = 0; r < 4; ++r)
            foutS[fm * 16 + lg * 4 + r][wn * 64 + fn * 16 + lr] =
                acc[fm][fn][r] + biasv[fn];
    }
    __syncthreads();
#pragma unroll
    for (int i = 0; i < 8; ++i) {
      int row = i * 8 + (t >> 5);
      int c0 = (t & 31) * 4;
      *(float4*)&out[(size_t)(mBase + ph * 64 + row) * 1024 + jBase + c0] =
          *(const float4*)&foutS[row][c0];
    }
  }
}

}  // namespace

extern "C" void kernel_launch(void* const* d_in, const int* in_sizes, int n_in,
                              void* d_out, int out_size, void* d_ws,
                              size_t ws_size, hipStream_t stream) {
  const float *x = nullptr, *Wqkv = nullptr, *bqkv = nullptr;
  const float *Wproj = nullptr, *bproj = nullptr, *Wrm = nullptr;
  for (int i = 0; i < n_in; ++i) {
    switch (in_sizes[i]) {
      case 16777216: x     = (const float*)d_in[i]; break;
      case 3145728:  Wqkv  = (const float*)d_in[i]; break;
      case 3072:     bqkv  = (const float*)d_in[i]; break;
      case 1048576:  Wproj = (const float*)d_in[i]; break;
      case 1024:     bproj = (const float*)d_in[i]; break;
      case 16384:    Wrm   = (const float*)d_in[i]; break;
      default: break;
    }
  }
  float* out = (float*)d_out;
  float* ws = (float*)d_ws;

  if (!x || !Wqkv || !bqkv || !Wproj || !bproj || !Wrm) {
    k_sent<<<1, 1, 0, stream>>>(out, 2000.0f);
    return;
  }
  if (ws_size < WS_ELEMS * sizeof(float)) {
    k_sent<<<1, 1, 0, stream>>>(out, 1000.0f);
    return;
  }

  unsigned short* vb   = (unsigned short*)(ws + V_OFF);
  unsigned short* xh   = (unsigned short*)(ws + XH_OFF);
  unsigned short* kvp  = (unsigned short*)(ws + KVP_OFF);
  unsigned short* kvt  = (unsigned short*)(ws + KVT_OFF);
  unsigned short* ambf = (unsigned short*)(ws + ATTNB_OFF);
  unsigned short* wh   = (unsigned short*)(ws + WH_OFF);
  unsigned short* wl   = (unsigned short*)(ws + WL_OFF);
  unsigned short* wrmh = (unsigned short*)(ws + WRMH_OFF);
  unsigned short* wrml = (unsigned short*)(ws + WRML_OFF);
  unsigned short* wph  = (unsigned short*)(ws + WPH_OFF);

  // conversions (once, all batches)
  k_conv_split<<<3072, 256, 0, stream>>>(Wqkv, wh, wl, 786432);
  k_conv_split<<<16, 256, 0, stream>>>(Wrm, wrmh, wrml, 4096);
  k_conv_hi<<<1024, 256, 0, stream>>>(Wproj, wph, 262144);
  k_conv_hi<<<16384, 256, 0, stream>>>(x, xh, 4194304);

  // all-batch fused pipeline (merged qkv: q/k split-path + v plain-path)
  k_qkv_all<<<dim3(24, 128), 256, 0, stream>>>(xh, wh, wl, bqkv, ws, vb);
  k_pass_a_mfma<<<dim3(16, 16, 4), 256, 0, stream>>>(ws, vb, wrmh, wrml,
                                                     kvp, ws + DPART_OFF);
  k_reduce_t<<<dim3(8, 16, 4), 256, 0, stream>>>(kvp, ws + DPART_OFF,
                                                 kvt, ws + DENV_OFF);
  k_pass_b_mfma<<<dim3(32, 16, 4), 256, 0, stream>>>(ws, wrmh, wrml, kvt,
                                                     ws + DENV_OFF, ambf);
  k_out_mfma<<<dim3(8, 128), 256, 0, stream>>>(ambf, wph, bproj, out);
}

// Round 14
// 361.478 us; speedup vs baseline: 1.1614x; 1.0244x over previous
//
#include <hip/hip_runtime.h>
#include <hip/hip_bf16.h>

namespace {

typedef __attribute__((ext_vector_type(8))) short short8v;   // 8 bf16
typedef __attribute__((ext_vector_type(4))) float float4v;   // 4 f32

// ---- workspace layout (float-slot offsets), ALL-BATCH fused (r10 proven) ----
constexpr size_t QB1      = 4194304;                 // 16h*4096*64 per batch
constexpr size_t Q_OFF    = 0;                       // f32 [4][16h][4096][64]
constexpr size_t K_OFF    = 16777216;                // f32 [4][16h][4096][64]
constexpr size_t ATTNB_OFF = K_OFF;                  // ushort overlay (K dead)
constexpr size_t V_OFF    = 33554432;                // ushort [4][16h][4096][64]
constexpr size_t XH_OFF   = 41943040;                // ushort [16384][1024]
constexpr size_t KVP_OFF  = XH_OFF;                  // ushort overlay (xh dead)
constexpr size_t DPART_OFF = 50331648;               // f32 [4][16nc][16h][256]
constexpr size_t KVT_OFF  = DPART_OFF + 262144;      // ushort [4][16h][64][256]
constexpr size_t DENV_OFF = KVT_OFF + 524288;        // f32 [4][16h][256]
constexpr size_t WH_OFF   = DENV_OFF + 16384;        // ushort Wqkv hi
constexpr size_t WL_OFF   = WH_OFF + 1572864;        // ushort Wqkv lo
constexpr size_t WRMH_OFF = WL_OFF + 1572864;        // ushort Wrm hi
constexpr size_t WRML_OFF = WRMH_OFF + 8192;
constexpr size_t WPH_OFF  = WRML_OFF + 8192;         // ushort Wproj hi
constexpr size_t WS_ELEMS = WPH_OFF + 524288;        // 54,820,864 (~219.3 MB)

__device__ __forceinline__ unsigned short f2bf(float f) {
  unsigned int u = __float_as_uint(f);
  u += 0x7FFFu + ((u >> 16) & 1u);                   // round-to-nearest-even
  return (unsigned short)(u >> 16);
}
__device__ __forceinline__ float bf2f(unsigned short u) {
  return __uint_as_float((unsigned)u << 16);
}

__global__ void k_sent(float* out, float v) { out[0] = v; }

// ---------------- merged conversions: x->hi, Wqkv->hi/lo, Wproj->hi, Wrm->hi/lo
// regions by float4-group index: x 4194304 | Wqkv 786432 | Wproj 262144 | Wrm 4096
__global__ __launch_bounds__(256) void k_conv_all(
    const float* __restrict__ x, const float* __restrict__ Wqkv,
    const float* __restrict__ Wproj, const float* __restrict__ Wrm,
    unsigned short* __restrict__ xh, unsigned short* __restrict__ wh,
    unsigned short* __restrict__ wl, unsigned short* __restrict__ wph,
    unsigned short* __restrict__ wrmh, unsigned short* __restrict__ wrml) {
  size_t i = (size_t)blockIdx.x * 256 + threadIdx.x;
  const float* src;
  unsigned short *hi, *lo = nullptr;
  size_t j;
  if (i < 4194304) {                   // x -> xh (hi only)
    j = i; src = x; hi = xh;
  } else if (i < 4194304 + 786432) {   // Wqkv -> wh/wl
    j = i - 4194304; src = Wqkv; hi = wh; lo = wl;
  } else if (i < 4194304 + 786432 + 262144) {  // Wproj -> wph (hi only)
    j = i - 4194304 - 786432; src = Wproj; hi = wph;
  } else if (i < 4194304 + 786432 + 262144 + 4096) {  // Wrm -> wrmh/wrml
    j = i - 4194304 - 786432 - 262144; src = Wrm; hi = wrmh; lo = wrml;
  } else {
    return;
  }
  float4 v = *(const float4*)&src[j * 4];
  ushort4 h;
  h.x = f2bf(v.x); h.y = f2bf(v.y); h.z = f2bf(v.z); h.w = f2bf(v.w);
  *(ushort4*)&hi[j * 4] = h;
  if (lo) {
    ushort4 l;
    l.x = f2bf(v.x - bf2f(h.x)); l.y = f2bf(v.y - bf2f(h.y));
    l.z = f2bf(v.z - bf2f(h.z)); l.w = f2bf(v.w - bf2f(h.w));
    *(ushort4*)&lo[j * 4] = l;
  }
}

// ---- stage [128 rows][64 k] bf16 tile via global_load_lds (verified) ----
__device__ __forceinline__ void stage_tile(const unsigned short* __restrict__ src,
                                           unsigned short* __restrict__ dst,
                                           int t) {
#pragma unroll
  for (int i = 0; i < 4; ++i) {
    int c = i * 256 + t;
    int row = c >> 3;
    int seg = (c & 7) ^ (row & 7);
    __builtin_amdgcn_global_load_lds(
        (const __attribute__((address_space(1))) void*)(src + (size_t)row * 1024 + seg * 8),
        (__attribute__((address_space(3))) void*)(dst + (size_t)c * 8),
        16, 0, 0);
  }
}

__device__ __forceinline__ short8v read_frag(const unsigned short* lds, int row,
                                             int seg) {
  return *(const short8v*)&lds[(size_t)row * 64 + ((seg ^ (row & 7)) * 8)];
}

// ---------------- qkv GEMM q/k (j<2048): 2-MFMA, all batches (r10 verbatim,
// launch_bounds min 3 blocks/CU: 48KB LDS x3 = 144 <= 160, VGPR 72 <= 170 cap)
__global__ __launch_bounds__(256, 3) void k_qkv_mfma(
    const unsigned short* __restrict__ xh,
    const unsigned short* __restrict__ wh, const unsigned short* __restrict__ wl,
    const float* __restrict__ bq, float* __restrict__ ws) {
  __shared__ unsigned short ldsA[8192];
  __shared__ unsigned short ldsB[2][8192];
  const int t = threadIdx.x;
  const int lane = t & 63, wv = t >> 6;
  const int wm = wv >> 1, wn = wv & 1;
  const int lr = lane & 15, lg = lane >> 4;
  const int mBase = blockIdx.y * 128;           // global row 0..16383
  const int jBase = blockIdx.x * 128;           // < 2048 (q/k)
  const int gb = mBase >> 12;
  const int nn0 = mBase & 4095;
  float4v acc[4][4];
#pragma unroll
  for (int a = 0; a < 4; ++a)
#pragma unroll
    for (int b = 0; b < 4; ++b) acc[a][b] = (float4v){0.f, 0.f, 0.f, 0.f};

  for (int kt = 0; kt < 1024; kt += 64) {
    __syncthreads();
    stage_tile(xh + (size_t)mBase * 1024 + kt, ldsA, t);
    stage_tile(wh + (size_t)jBase * 1024 + kt, ldsB[0], t);
    stage_tile(wl + (size_t)jBase * 1024 + kt, ldsB[1], t);
    asm volatile("s_waitcnt vmcnt(0)");
    __syncthreads();
#pragma unroll
    for (int ks = 0; ks < 2; ++ks) {
      const int seg = ks * 4 + lg;
      short8v ah[4], bh[4], bl[4];
#pragma unroll
      for (int f = 0; f < 4; ++f) {
        ah[f] = read_frag(ldsA, wm * 64 + f * 16 + lr, seg);
        int rb = wn * 64 + f * 16 + lr;
        bh[f] = read_frag(ldsB[0], rb, seg);
        bl[f] = read_frag(ldsB[1], rb, seg);
      }
#pragma unroll
      for (int fm = 0; fm < 4; ++fm)
#pragma unroll
        for (int fn = 0; fn < 4; ++fn) {
          acc[fm][fn] = __builtin_amdgcn_mfma_f32_16x16x32_bf16(
              ah[fm], bh[fn], acc[fm][fn], 0, 0, 0);
          acc[fm][fn] = __builtin_amdgcn_mfma_f32_16x16x32_bf16(
              ah[fm], bl[fn], acc[fm][fn], 0, 0, 0);
        }
    }
  }
#pragma unroll
  for (int fn = 0; fn < 4; ++fn) {
    int j = jBase + wn * 64 + fn * 16 + lr;
    int t3 = j >> 10, h = (j >> 6) & 15, dd = j & 63;
    float bias = bq[j];
    float* op = ws + (t3 ? K_OFF : Q_OFF) + (size_t)gb * QB1 +
                (size_t)h * 262144 + dd;
#pragma unroll
    for (int fm = 0; fm < 4; ++fm) {
      int n0 = nn0 + wm * 64 + fm * 16 + lg * 4;
#pragma unroll
      for (int r = 0; r < 4; ++r)
        op[(size_t)(n0 + r) * 64] = acc[fm][fn][r] + bias;
    }
  }
}

// ---------------- qkv GEMM v (j in [2048,3072)): plain bf16 (r10 verbatim,
// min 4 blocks/CU: 32KB LDS x4 = 128 <= 160, VGPR 60 <= 128 cap)
__global__ __launch_bounds__(256, 4) void k_qkv_v(
    const unsigned short* __restrict__ xh, const unsigned short* __restrict__ wh,
    const float* __restrict__ bq, unsigned short* __restrict__ vb) {
  __shared__ unsigned short ldsA[8192];
  __shared__ unsigned short ldsB[8192];
  const int t = threadIdx.x;
  const int lane = t & 63, wv = t >> 6;
  const int wm = wv >> 1, wn = wv & 1;
  const int lr = lane & 15, lg = lane >> 4;
  const int mBase = blockIdx.y * 128;
  const int jBase = 2048 + blockIdx.x * 128;
  const int gb = mBase >> 12;
  const int nn0 = mBase & 4095;
  float4v acc[4][4];
#pragma unroll
  for (int a = 0; a < 4; ++a)
#pragma unroll
    for (int b = 0; b < 4; ++b) acc[a][b] = (float4v){0.f, 0.f, 0.f, 0.f};

  for (int kt = 0; kt < 1024; kt += 64) {
    __syncthreads();
    stage_tile(xh + (size_t)mBase * 1024 + kt, ldsA, t);
    stage_tile(wh + (size_t)jBase * 1024 + kt, ldsB, t);
    asm volatile("s_waitcnt vmcnt(0)");
    __syncthreads();
#pragma unroll
    for (int ks = 0; ks < 2; ++ks) {
      const int seg = ks * 4 + lg;
      short8v a[4], b[4];
#pragma unroll
      for (int f = 0; f < 4; ++f) {
        a[f] = read_frag(ldsA, wm * 64 + f * 16 + lr, seg);
        b[f] = read_frag(ldsB, wn * 64 + f * 16 + lr, seg);
      }
#pragma unroll
      for (int fm = 0; fm < 4; ++fm)
#pragma unroll
        for (int fn = 0; fn < 4; ++fn)
          acc[fm][fn] = __builtin_amdgcn_mfma_f32_16x16x32_bf16(
              a[fm], b[fn], acc[fm][fn], 0, 0, 0);
    }
  }
#pragma unroll
  for (int fn = 0; fn < 4; ++fn) {
    int j = jBase + wn * 64 + fn * 16 + lr;
    int h = (j >> 6) & 15, dd = j & 63;
    float bias = bq[j];
    unsigned short* op = vb + (size_t)gb * 4194304 + (size_t)h * 262144 + dd;
#pragma unroll
    for (int fm = 0; fm < 4; ++fm) {
      int n0 = nn0 + wm * 64 + fm * 16 + lg * 4;
#pragma unroll
      for (int r = 0; r < 4; ++r)
        op[(size_t)(n0 + r) * 64] = f2bf(acc[fm][fn][r] + bias);
    }
  }
}

// ---------------- pass A: fused phi_k (split MFMA) + KV MFMA, batched z (r10)
__global__ __launch_bounds__(256) void k_pass_a_mfma(
    const float* __restrict__ ws, const unsigned short* __restrict__ vbb,
    const unsigned short* __restrict__ wrmh,
    const unsigned short* __restrict__ wrml, unsigned short* __restrict__ kvp,
    float* __restrict__ dpart) {
  __shared__ __align__(16) unsigned short khi[32][72];
  __shared__ __align__(16) unsigned short klo[32][72];
  __shared__ __align__(16) unsigned short vT[64][40];
  __shared__ __align__(16) unsigned short phL[256][40];
  __shared__ __align__(16) float nsL[32];
  const int t = threadIdx.x;
  const int lane = t & 63, wv = t >> 6;
  const int lr = lane & 15, lg = lane >> 4;
  const int nc = blockIdx.x, h = blockIdx.y, gb = blockIdx.z;
  const float* kb = ws + K_OFF + (size_t)gb * QB1 + (size_t)h * 262144;
  const unsigned short* vbh = vbb + (size_t)gb * 4194304 + (size_t)h * 262144;
  float4v acc[4][4];
#pragma unroll
  for (int a = 0; a < 4; ++a)
#pragma unroll
    for (int b = 0; b < 4; ++b) acc[a][b] = (float4v){0.f, 0.f, 0.f, 0.f};
  float dacc[4] = {};

  for (int tile = 0; tile < 8; ++tile) {
    const int n0 = nc * 256 + tile * 32;
    __syncthreads();
    {  // stage k hi/lo + ns
      int sn = t >> 3, sd = (t & 7) * 8;
      const float* kp = kb + (size_t)(n0 + sn) * 64 + sd;
      float4 a0 = *(const float4*)kp;
      float4 a1 = *(const float4*)(kp + 4);
      float vv[8] = {a0.x, a0.y, a0.z, a0.w, a1.x, a1.y, a1.z, a1.w};
      short8v hv, lv;
      float ss = 0.f;
#pragma unroll
      for (int j = 0; j < 8; ++j) {
        ss += vv[j] * vv[j];
        unsigned short hu = f2bf(vv[j]);
        hv[j] = (short)hu;
        lv[j] = (short)f2bf(vv[j] - bf2f(hu));
      }
      *(short8v*)&khi[sn][sd] = hv;
      *(short8v*)&klo[sn][sd] = lv;
      ss += __shfl_xor(ss, 1); ss += __shfl_xor(ss, 2); ss += __shfl_xor(ss, 4);
      if ((t & 7) == 0) nsL[sn] = 0.5f * ss;
    }
    {  // stage v (bf16) transposed
      int sn = t & 31, sd = (t >> 5) * 8;
      short8v v8 = *(const short8v*)&vbh[(size_t)(n0 + sn) * 64 + sd];
#pragma unroll
      for (int j = 0; j < 8; ++j) vT[sd + j][sn] = (unsigned short)v8[j];
    }
    __syncthreads();
    float4v p[2][4];
#pragma unroll
    for (int a = 0; a < 2; ++a)
#pragma unroll
      for (int b = 0; b < 4; ++b) p[a][b] = (float4v){0.f, 0.f, 0.f, 0.f};
#pragma unroll
    for (int ks = 0; ks < 2; ++ks) {
      short8v ah[2], al[2];
#pragma unroll
      for (int nf = 0; nf < 2; ++nf) {
        ah[nf] = *(const short8v*)&khi[nf * 16 + lr][ks * 32 + lg * 8];
        al[nf] = *(const short8v*)&klo[nf * 16 + lr][ks * 32 + lg * 8];
      }
#pragma unroll
      for (int rf = 0; rf < 4; ++rf) {
        size_t wo = (size_t)(wv * 64 + rf * 16 + lr) * 64 + ks * 32 + lg * 8;
        short8v bh = *(const short8v*)&wrmh[wo];
        short8v bl = *(const short8v*)&wrml[wo];
#pragma unroll
        for (int nf = 0; nf < 2; ++nf) {
          p[nf][rf] = __builtin_amdgcn_mfma_f32_16x16x32_bf16(ah[nf], bh, p[nf][rf], 0, 0, 0);
          p[nf][rf] = __builtin_amdgcn_mfma_f32_16x16x32_bf16(ah[nf], bl, p[nf][rf], 0, 0, 0);
          p[nf][rf] = __builtin_amdgcn_mfma_f32_16x16x32_bf16(al[nf], bh, p[nf][rf], 0, 0, 0);
        }
      }
    }
#pragma unroll
    for (int nf = 0; nf < 2; ++nf) {
      float4 ns4 = *(const float4*)&nsL[nf * 16 + lg * 4];
      float nsa[4] = {ns4.x, ns4.y, ns4.z, ns4.w};
#pragma unroll
      for (int rf = 0; rf < 4; ++rf) {
        ushort4 u;
        float s = 0.f;
        unsigned short uu;
        uu = f2bf(__expf(p[nf][rf][0] - nsa[0]) * 0.0625f); u.x = uu; s += bf2f(uu);
        uu = f2bf(__expf(p[nf][rf][1] - nsa[1]) * 0.0625f); u.y = uu; s += bf2f(uu);
        uu = f2bf(__expf(p[nf][rf][2] - nsa[2]) * 0.0625f); u.z = uu; s += bf2f(uu);
        uu = f2bf(__expf(p[nf][rf][3] - nsa[3]) * 0.0625f); u.w = uu; s += bf2f(uu);
        dacc[rf] += s;
        *(ushort4*)&phL[wv * 64 + rf * 16 + lr][nf * 16 + lg * 4] = u;
      }
    }
    {
      short8v af[4], bf_[4];
#pragma unroll
      for (int rf = 0; rf < 4; ++rf)
        af[rf] = *(const short8v*)&phL[wv * 64 + rf * 16 + lr][lg * 8];
#pragma unroll
      for (int df = 0; df < 4; ++df)
        bf_[df] = *(const short8v*)&vT[df * 16 + lr][lg * 8];
#pragma unroll
      for (int rf = 0; rf < 4; ++rf)
#pragma unroll
        for (int df = 0; df < 4; ++df)
          acc[rf][df] = __builtin_amdgcn_mfma_f32_16x16x32_bf16(
              af[rf], bf_[df], acc[rf][df], 0, 0, 0);
    }
  }
  size_t rbase = (((size_t)gb * 16 + nc) * 16 + h) * 256;
#pragma unroll
  for (int rf = 0; rf < 4; ++rf) {
#pragma unroll
    for (int df = 0; df < 4; ++df)
#pragma unroll
      for (int i = 0; i < 4; ++i) {
        int r = wv * 64 + rf * 16 + lg * 4 + i;
        kvp[(rbase + r) * 64 + df * 16 + lr] = f2bf(acc[rf][df][i]);
      }
    float dv2 = dacc[rf];
    dv2 += __shfl_xor(dv2, 16);
    dv2 += __shfl_xor(dv2, 32);
    if (lg == 0) dpart[rbase + wv * 64 + rf * 16 + lr] = dv2;
  }
}

// ---------------- reduce bf16 partials -> KV^T bf16 + denv, batched z (r10)
__global__ __launch_bounds__(256) void k_reduce_t(
    const unsigned short* __restrict__ kvp, const float* __restrict__ dpart,
    unsigned short* __restrict__ kvt, float* __restrict__ denv) {
  __shared__ __align__(16) float tile[32][69];
  const int rb = blockIdx.x, h = blockIdx.y, gb = blockIdx.z;
  const int t = threadIdx.x;
  const int rl = t >> 3, sd = (t & 7) * 8;
  float s[8] = {};
  for (int c = 0; c < 16; ++c) {
    const unsigned short* p = kvp +
        ((((size_t)gb * 16 + c) * 16 + h) * 256 + rb * 32 + rl) * 64 + sd;
    short8v b8 = *(const short8v*)p;
#pragma unroll
    for (int j = 0; j < 8; ++j) s[j] += bf2f((unsigned short)b8[j]);
  }
#pragma unroll
  for (int j = 0; j < 8; ++j) tile[rl][sd + j] = s[j];
  __syncthreads();
  int d = t >> 2, rj = (t & 3) * 8;
  short8v u;
#pragma unroll
  for (int j = 0; j < 8; ++j) u[j] = (short)f2bf(tile[rj + j][d]);
  *(short8v*)&kvt[(((size_t)gb * 16 + h) * 64 + d) * 256 + rb * 32 + rj] = u;
  if (rb == 0) {
    float sum = 0.f;
    for (int c = 0; c < 16; ++c)
      sum += dpart[(((size_t)gb * 16 + c) * 16 + h) * 256 + t];
    denv[((size_t)gb * 16 + h) * 256 + t] = sum;
  }
}

// ---------------- pass B: fused phi_q (split MFMA) + PV MFMA, batched z (r10)
__global__ __launch_bounds__(256) void k_pass_b_mfma(
    const float* __restrict__ ws, const unsigned short* __restrict__ wrmh,
    const unsigned short* __restrict__ wrml,
    const unsigned short* __restrict__ kvt, const float* __restrict__ denv,
    unsigned short* __restrict__ attnb) {
  __shared__ __align__(16) unsigned short kvL[64][264];
  __shared__ __align__(16) unsigned short phL[32][264];
  __shared__ __align__(16) unsigned short qhi[32][72];
  __shared__ __align__(16) unsigned short qlo[32][72];
  __shared__ __align__(16) unsigned short outL[32][80];
  __shared__ __align__(16) float denvL[256];
  __shared__ __align__(16) float nsL[32];
  __shared__ float denp[4][32];
  __shared__ float invL[32];
  const int t = threadIdx.x;
  const int lane = t & 63, wv = t >> 6;
  const int lr = lane & 15, lg = lane >> 4;
  const int nc = blockIdx.x, h = blockIdx.y, gb = blockIdx.z;
  const float* qb = ws + Q_OFF + (size_t)gb * QB1 + (size_t)h * 262144;
  unsigned short* ao = attnb + (size_t)gb * 4194304;
  {
    const unsigned short* src =
        kvt + ((size_t)gb * 16 + h) * 16384 + (size_t)t * 64;
    int d = t >> 2, r0 = (t & 3) * 64;
#pragma unroll
    for (int j = 0; j < 8; ++j)
      *(short8v*)&kvL[d][r0 + j * 8] = *(const short8v*)(src + j * 8);
    denvL[t] = denv[((size_t)gb * 16 + h) * 256 + t];
  }
  for (int tile = 0; tile < 4; ++tile) {
    const int n0 = nc * 128 + tile * 32;
    __syncthreads();
    {  // stage q hi/lo + ns
      int sn = t >> 3, sd = (t & 7) * 8;
      const float* qp = qb + (size_t)(n0 + sn) * 64 + sd;
      float4 a0 = *(const float4*)qp;
      float4 a1 = *(const float4*)(qp + 4);
      float vv[8] = {a0.x, a0.y, a0.z, a0.w, a1.x, a1.y, a1.z, a1.w};
      short8v hv, lv;
      float ss = 0.f;
#pragma unroll
      for (int j = 0; j < 8; ++j) {
        ss += vv[j] * vv[j];
        unsigned short hu = f2bf(vv[j]);
        hv[j] = (short)hu;
        lv[j] = (short)f2bf(vv[j] - bf2f(hu));
      }
      *(short8v*)&qhi[sn][sd] = hv;
      *(short8v*)&qlo[sn][sd] = lv;
      ss += __shfl_xor(ss, 1); ss += __shfl_xor(ss, 2); ss += __shfl_xor(ss, 4);
      if ((t & 7) == 0) nsL[sn] = 0.5f * ss;
    }
    __syncthreads();
    float4v p[4][2];
#pragma unroll
    for (int a = 0; a < 4; ++a)
#pragma unroll
      for (int b = 0; b < 2; ++b) p[a][b] = (float4v){0.f, 0.f, 0.f, 0.f};
#pragma unroll
    for (int ks = 0; ks < 2; ++ks) {
      short8v bh[2], bl[2];
#pragma unroll
      for (int nf = 0; nf < 2; ++nf) {
        bh[nf] = *(const short8v*)&qhi[nf * 16 + lr][ks * 32 + lg * 8];
        bl[nf] = *(const short8v*)&qlo[nf * 16 + lr][ks * 32 + lg * 8];
      }
#pragma unroll
      for (int rf = 0; rf < 4; ++rf) {
        size_t wo = (size_t)(wv * 64 + rf * 16 + lr) * 64 + ks * 32 + lg * 8;
        short8v ah = *(const short8v*)&wrmh[wo];
        short8v al = *(const short8v*)&wrml[wo];
#pragma unroll
        for (int nf = 0; nf < 2; ++nf) {
          p[rf][nf] = __builtin_amdgcn_mfma_f32_16x16x32_bf16(ah, bh[nf], p[rf][nf], 0, 0, 0);
          p[rf][nf] = __builtin_amdgcn_mfma_f32_16x16x32_bf16(al, bh[nf], p[rf][nf], 0, 0, 0);
          p[rf][nf] = __builtin_amdgcn_mfma_f32_16x16x32_bf16(ah, bl[nf], p[rf][nf], 0, 0, 0);
        }
      }
    }
    float dnp[2] = {0.f, 0.f};
#pragma unroll
    for (int nf = 0; nf < 2; ++nf) {
      float ns = nsL[nf * 16 + lr];
#pragma unroll
      for (int rf = 0; rf < 4; ++rf) {
        float4 dv4 = *(const float4*)&denvL[wv * 64 + rf * 16 + lg * 4];
        float da[4] = {dv4.x, dv4.y, dv4.z, dv4.w};
        ushort4 u;
        unsigned short uu;
        float s = 0.f;
        uu = f2bf(__expf(p[rf][nf][0] - ns) * 0.0625f); u.x = uu; s += bf2f(uu) * da[0];
        uu = f2bf(__expf(p[rf][nf][1] - ns) * 0.0625f); u.y = uu; s += bf2f(uu) * da[1];
        uu = f2bf(__expf(p[rf][nf][2] - ns) * 0.0625f); u.z = uu; s += bf2f(uu) * da[2];
        uu = f2bf(__expf(p[rf][nf][3] - ns) * 0.0625f); u.w = uu; s += bf2f(uu) * da[3];
        dnp[nf] += s;
        *(ushort4*)&phL[nf * 16 + lr][wv * 64 + rf * 16 + lg * 4] = u;
      }
    }
#pragma unroll
    for (int nf = 0; nf < 2; ++nf) {
      float v2 = dnp[nf];
      v2 += __shfl_xor(v2, 16);
      v2 += __shfl_xor(v2, 32);
      if (lg == 0) denp[wv][nf * 16 + lr] = v2;
    }
    __syncthreads();
    if (t < 32) {
      float dn = denp[0][t] + denp[1][t] + denp[2][t] + denp[3][t];
      invL[t] = 1.0f / (dn + 1e-6f);
    }
    __syncthreads();
    const int nfj = wv & 1;
    float4v o[2];
    o[0] = (float4v){0.f, 0.f, 0.f, 0.f};
    o[1] = (float4v){0.f, 0.f, 0.f, 0.f};
#pragma unroll
    for (int ks = 0; ks < 8; ++ks) {
      short8v af = *(const short8v*)&phL[nfj * 16 + lr][ks * 32 + lg * 8];
#pragma unroll
      for (int j = 0; j < 2; ++j) {
        int df = (wv >> 1) * 2 + j;
        short8v bfr = *(const short8v*)&kvL[df * 16 + lr][ks * 32 + lg * 8];
        o[j] = __builtin_amdgcn_mfma_f32_16x16x32_bf16(af, bfr, o[j], 0, 0, 0);
      }
    }
#pragma unroll
    for (int j = 0; j < 2; ++j) {
      int df = (wv >> 1) * 2 + j;
#pragma unroll
      for (int i = 0; i < 4; ++i) {
        int n = nfj * 16 + lg * 4 + i;
        outL[n][df * 16 + lr] = f2bf(o[j][i] * invL[n]);
      }
    }
    __syncthreads();
    {
      int sn = t >> 3, sd = (t & 7) * 8;
      short8v v8 = *(const short8v*)&outL[sn][sd];
      *(short8v*)&ao[((size_t)(n0 + sn)) * 1024 + h * 64 + sd] = v8;
    }
  }
}

// ---------------- out GEMM: XCD remap + LDS-staged full-line writes (r10)
__global__ __launch_bounds__(256, 2) void k_out_mfma(
    const unsigned short* __restrict__ ab, const unsigned short* __restrict__ wp,
    const float* __restrict__ bp, float* __restrict__ out) {
  __shared__ unsigned short ldsA[8192];
  __shared__ unsigned short ldsB[8192];
  __shared__ __align__(16) float foutS[64][132];
  const int t = threadIdx.x;
  const int lane = t & 63, wv = t >> 6;
  const int wm = wv >> 1, wn = wv & 1;
  const int lr = lane & 15, lg = lane >> 4;
  const int flat = blockIdx.y * 8 + blockIdx.x;       // grid (8,128)
  const int mBase = (flat & 127) * 128;
  const int jBase = (flat >> 7) * 128;
  float4v acc[4][4];
#pragma unroll
  for (int a = 0; a < 4; ++a)
#pragma unroll
    for (int b = 0; b < 4; ++b) acc[a][b] = (float4v){0.f, 0.f, 0.f, 0.f};

  for (int kt = 0; kt < 1024; kt += 64) {
    __syncthreads();
    stage_tile(ab + (size_t)mBase * 1024 + kt, ldsA, t);
    stage_tile(wp + (size_t)jBase * 1024 + kt, ldsB, t);
    asm volatile("s_waitcnt vmcnt(0)");
    __syncthreads();
#pragma unroll
    for (int ks = 0; ks < 2; ++ks) {
      const int seg = ks * 4 + lg;
      short8v a[4], b[4];
#pragma unroll
      for (int f = 0; f < 4; ++f) {
        a[f] = read_frag(ldsA, wm * 64 + f * 16 + lr, seg);
        b[f] = read_frag(ldsB, wn * 64 + f * 16 + lr, seg);
      }
#pragma unroll
      for (int fm = 0; fm < 4; ++fm)
#pragma unroll
        for (int fn = 0; fn < 4; ++fn)
          acc[fm][fn] = __builtin_amdgcn_mfma_f32_16x16x32_bf16(
              a[fm], b[fn], acc[fm][fn], 0, 0, 0);
    }
  }
  float biasv[4];
#pragma unroll
  for (int fn = 0; fn < 4; ++fn)
    biasv[fn] = bp[jBase + wn * 64 + fn * 16 + lr];
#pragma unroll
  for (int ph = 0; ph < 2; ++ph) {
    __syncthreads();
    if (wm == ph) {
#pragma unroll
      for (int fm = 0; fm < 4; ++fm)
#pragma unroll
        for (int fn = 0; fn < 4; ++fn)
#pragma unroll
          for (int r = 0; r < 4; ++r)
            foutS[fm * 16 + lg * 4 + r][wn * 64 + fn * 16 + lr] =
                acc[fm][fn][r] + biasv[fn];
    }
    __syncthreads();
#pragma unroll
    for (int i = 0; i < 8; ++i) {
      int row = i * 8 + (t >> 5);
      int c0 = (t & 31) * 4;
      *(float4*)&out[(size_t)(mBase + ph * 64 + row) * 1024 + jBase + c0] =
          *(const float4*)&foutS[row][c0];
    }
  }
}

}  // namespace

extern "C" void kernel_launch(void* const* d_in, const int* in_sizes, int n_in,
                              void* d_out, int out_size, void* d_ws,
                              size_t ws_size, hipStream_t stream) {
  const float *x = nullptr, *Wqkv = nullptr, *bqkv = nullptr;
  const float *Wproj = nullptr, *bproj = nullptr, *Wrm = nullptr;
  for (int i = 0; i < n_in; ++i) {
    switch (in_sizes[i]) {
      case 16777216: x     = (const float*)d_in[i]; break;
      case 3145728:  Wqkv  = (const float*)d_in[i]; break;
      case 3072:     bqkv  = (const float*)d_in[i]; break;
      case 1048576:  Wproj = (const float*)d_in[i]; break;
      case 1024:     bproj = (const float*)d_in[i]; break;
      case 16384:    Wrm   = (const float*)d_in[i]; break;
      default: break;
    }
  }
  float* out = (float*)d_out;
  float* ws = (float*)d_ws;

  if (!x || !Wqkv || !bqkv || !Wproj || !bproj || !Wrm) {
    k_sent<<<1, 1, 0, stream>>>(out, 2000.0f);
    return;
  }
  if (ws_size < WS_ELEMS * sizeof(float)) {
    k_sent<<<1, 1, 0, stream>>>(out, 1000.0f);
    return;
  }

  unsigned short* vb   = (unsigned short*)(ws + V_OFF);
  unsigned short* xh   = (unsigned short*)(ws + XH_OFF);
  unsigned short* kvp  = (unsigned short*)(ws + KVP_OFF);
  unsigned short* kvt  = (unsigned short*)(ws + KVT_OFF);
  unsigned short* ambf = (unsigned short*)(ws + ATTNB_OFF);
  unsigned short* wh   = (unsigned short*)(ws + WH_OFF);
  unsigned short* wl   = (unsigned short*)(ws + WL_OFF);
  unsigned short* wrmh = (unsigned short*)(ws + WRMH_OFF);
  unsigned short* wrml = (unsigned short*)(ws + WRML_OFF);
  unsigned short* wph  = (unsigned short*)(ws + WPH_OFF);

  // all conversions in ONE launch (x, Wqkv, Wproj, Wrm): 5,246,976 f4-groups
  k_conv_all<<<20497, 256, 0, stream>>>(x, Wqkv, Wproj, Wrm, xh, wh, wl, wph,
                                        wrmh, wrml);

  // all-batch fused pipeline (r10-proven kernels)
  k_qkv_mfma<<<dim3(16, 128), 256, 0, stream>>>(xh, wh, wl, bqkv, ws);
  k_qkv_v<<<dim3(8, 128), 256, 0, stream>>>(xh, wh, bqkv, vb);
  k_pass_a_mfma<<<dim3(16, 16, 4), 256, 0, stream>>>(ws, vb, wrmh, wrml,
                                                     kvp, ws + DPART_OFF);
  k_reduce_t<<<dim3(8, 16, 4), 256, 0, stream>>>(kvp, ws + DPART_OFF,
                                                 kvt, ws + DENV_OFF);
  k_pass_b_mfma<<<dim3(32, 16, 4), 256, 0, stream>>>(ws, wrmh, wrml, kvt,
                                                     ws + DENV_OFF, ambf);
  k_out_mfma<<<dim3(8, 128), 256, 0, stream>>>(ambf, wph, bproj, out);
}